// Round 4
// baseline (117.224 us; speedup 1.0000x reference)
//
#include <hip/hip_runtime.h>

// Bicubic (Catmull-Rom) warped interpolation, LDS-tiled.
// img/delta_x/delta_y: [B,C,H,W] fp32; out: [B,C,H,W] fp32 clipped to [0,1].
// H = W = 1024. Tile: 64x64 output per 256-thread block; 80x80 image patch
// staged in LDS with row stride 97 (97 mod 32 == 1, so the data-dependent
// (dx,dy) jitter perturbs the lane->bank diagonal by only ~±3 -> ~2-3
// lanes/bank, nearly conflict-free; stride 84 == 20 mod 32 amplified row
// jitter x20 and randomized banks -> 2.4e7 conflict cycles).
// Lane = column (stride-1). Out-of-patch taps take a rare global fallback.

#define HD 1024
#define WD 1024
#define TILE 64
#define HALO 8
#define SROWS 80   // staged rows & cols of valid data
#define SSTR 97    // LDS row stride in floats; 97 % 32 == 1

__device__ __forceinline__ float cubic_gather_global(
    const float* __restrict__ p, int x0, int y0,
    float wxm1, float wx0, float wx1, float wx2,
    float wym1, float wy0, float wy1, float wy2)
{
    int cx0 = min(max(x0 - 1, 0), WD - 1);
    int cx1 = min(max(x0,     0), WD - 1);
    int cx2 = min(max(x0 + 1, 0), WD - 1);
    int cx3 = min(max(x0 + 2, 0), WD - 1);
    int cy0 = min(max(y0 - 1, 0), HD - 1);
    int cy1 = min(max(y0,     0), HD - 1);
    int cy2 = min(max(y0 + 1, 0), HD - 1);
    int cy3 = min(max(y0 + 2, 0), HD - 1);
    const float* r0 = p + (size_t)cy0 * WD;
    const float* r1 = p + (size_t)cy1 * WD;
    const float* r2 = p + (size_t)cy2 * WD;
    const float* r3 = p + (size_t)cy3 * WD;
    float s0 = wxm1 * r0[cx0] + wx0 * r0[cx1] + wx1 * r0[cx2] + wx2 * r0[cx3];
    float s1 = wxm1 * r1[cx0] + wx0 * r1[cx1] + wx1 * r1[cx2] + wx2 * r1[cx3];
    float s2 = wxm1 * r2[cx0] + wx0 * r2[cx1] + wx1 * r2[cx2] + wx2 * r2[cx3];
    float s3 = wxm1 * r3[cx0] + wx0 * r3[cx1] + wx1 * r3[cx2] + wx2 * r3[cx3];
    return wym1 * s0 + wy0 * s1 + wy1 * s2 + wy2 * s3;
}

__global__ __launch_bounds__(256) void bicubic_tile_kernel(
    const float* __restrict__ img,
    const float* __restrict__ dxp,
    const float* __restrict__ dyp,
    float* __restrict__ out)
{
    __shared__ float sm[SROWS * SSTR];

    const int bx = blockIdx.x * TILE;
    const int by = blockIdx.y * TILE;
    const int plane = blockIdx.z;
    const float* __restrict__ p = img + (size_t)plane * (size_t)(HD * WD);

    const int gx0 = bx - HALO;
    const int gy0 = by - HALO;
    const int tid = threadIdx.x;

    // ---- stage 80x80 patch at (gy0, gx0) into LDS (edge-clamped) ----
    if (gx0 >= 0 && gx0 + SROWS <= WD) {
        // interior in x: float4 global loads, scalar LDS writes (stride 97)
        for (int s = tid; s < SROWS * (SROWS / 4); s += 256) {
            int r = s / (SROWS / 4);
            int q = s - r * (SROWS / 4);
            int gy = min(max(gy0 + r, 0), HD - 1);
            float4 v = *reinterpret_cast<const float4*>(p + (size_t)gy * WD + gx0 + 4 * q);
            int b = r * SSTR + 4 * q;
            sm[b + 0] = v.x; sm[b + 1] = v.y; sm[b + 2] = v.z; sm[b + 3] = v.w;
        }
    } else {
        // x-edge tile: scalar staging with clamp
        for (int s = tid; s < SROWS * SROWS; s += 256) {
            int r = s / SROWS;
            int c = s - r * SROWS;
            int gy = min(max(gy0 + r, 0), HD - 1);
            int gx = min(max(gx0 + c, 0), WD - 1);
            sm[r * SSTR + c] = p[(size_t)gy * WD + gx];
        }
    }
    __syncthreads();

    // ---- compute: lane = column (64 consecutive cols/wave), 16 rows/thread
    const int col = bx + (tid & 63);
    const int rbase = by + (tid >> 6);

    // x_map = ((x + dx - 512)/511 + 1)*511.5 == (x - 512)*s + 511.5 + dx*s
    const float s = 511.5f / 511.0f;
    const float colA = ((float)col - 512.0f) * s + 511.5f;

    #pragma unroll 4
    for (int it = 0; it < 16; ++it) {
        const int y = rbase + it * 4;
        const int didx = (plane << 20) | (y << 10) | col;

        const float ddx = dxp[didx];
        const float ddy = dyp[didx];

        const float yA = ((float)y - 512.0f) * s + 511.5f;
        float x_map = fmaf(ddx, s, colA);
        float y_map = fmaf(ddy, s, yA);

        float x0f = floorf(x_map);
        float y0f = floorf(y_map);
        float tx = x_map - x0f;
        float ty = y_map - y0f;
        int x0 = (int)x0f;
        int y0 = (int)y0f;

        float tx2 = tx * tx, tx3 = tx2 * tx;
        float wxm1 = (-tx3 + 2.0f * tx2 - tx) * 0.5f;
        float wx0  = (3.0f * tx3 - 5.0f * tx2 + 2.0f) * 0.5f;
        float wx1  = (-3.0f * tx3 + 4.0f * tx2 + tx) * 0.5f;
        float wx2  = 1.0f - (wxm1 + wx0 + wx1);

        float ty2 = ty * ty, ty3 = ty2 * ty;
        float wym1 = (-ty3 + 2.0f * ty2 - ty) * 0.5f;
        float wy0  = (3.0f * ty3 - 5.0f * ty2 + 2.0f) * 0.5f;
        float wy1  = (-3.0f * ty3 + 4.0f * ty2 + ty) * 0.5f;
        float wy2  = 1.0f - (wym1 + wy0 + wy1);

        // raw tap window (LDS holds edge-clamped values; no per-tap clamps)
        const int lx = x0 - 1 - gx0;
        const int ly = y0 - 1 - gy0;
        const bool inb = (lx >= 0) & (lx <= SROWS - 4) & (ly >= 0) & (ly <= SROWS - 4);

        float acc;
        if (inb) {
            const float* b = &sm[ly * SSTR + lx];
            float s0 = wxm1 * b[0 * SSTR + 0] + wx0 * b[0 * SSTR + 1] + wx1 * b[0 * SSTR + 2] + wx2 * b[0 * SSTR + 3];
            float s1 = wxm1 * b[1 * SSTR + 0] + wx0 * b[1 * SSTR + 1] + wx1 * b[1 * SSTR + 2] + wx2 * b[1 * SSTR + 3];
            float s2 = wxm1 * b[2 * SSTR + 0] + wx0 * b[2 * SSTR + 1] + wx1 * b[2 * SSTR + 2] + wx2 * b[2 * SSTR + 3];
            float s3 = wxm1 * b[3 * SSTR + 0] + wx0 * b[3 * SSTR + 1] + wx1 * b[3 * SSTR + 2] + wx2 * b[3 * SSTR + 3];
            acc = wym1 * s0 + wy0 * s1 + wy1 * s2 + wy2 * s3;
        } else {
            acc = cubic_gather_global(p, x0, y0, wxm1, wx0, wx1, wx2,
                                      wym1, wy0, wy1, wy2);
        }
        out[didx] = fminf(fmaxf(acc, 0.0f), 1.0f);
    }
}

extern "C" void kernel_launch(void* const* d_in, const int* in_sizes, int n_in,
                              void* d_out, int out_size, void* d_ws, size_t ws_size,
                              hipStream_t stream) {
    const float* img = (const float*)d_in[0];
    const float* dxp = (const float*)d_in[1];
    const float* dyp = (const float*)d_in[2];
    float* out = (float*)d_out;

    const int planes = in_sizes[0] / (HD * WD);  // B*C = 24
    dim3 grid(WD / TILE, HD / TILE, planes);
    bicubic_tile_kernel<<<grid, 256, 0, stream>>>(img, dxp, dyp, out);
}